// Round 9
// baseline (229.615 us; speedup 1.0000x reference)
//
#include <hip/hip_runtime.h>
#include <math.h>

#define TT 512
#define DD 256
#define BIGF 9999.0f
#define KK 8

// ws layout (bytes)
#define HT_OFF    0          // float ht[DD][TT]   512 KB  transposed H
#define A_OFF     524288     // float a[TT]
#define B_OFF     526336     // float b[TT]
#define MB_OFF    528384     // ull   mb[TT][4]
#define MSEP_OFF  544768     // float msep4[128]

typedef unsigned long long ull;

__global__ __launch_bounds__(256) void prep_kernel(
    const float* __restrict__ X, const float* __restrict__ H,
    const float* __restrict__ C, const int* __restrict__ M,
    float* __restrict__ ht, float* __restrict__ A, float* __restrict__ B,
    ull* __restrict__ MB, float* __restrict__ MSEP4, float* __restrict__ out) {
  const int b = blockIdx.x;
  const int t = threadIdx.x;
  const int wid = t >> 6, lane = t & 63;
  const int i0 = 4 * b;
  if (b == 0 && t == 0) out[0] = 0.0f;  // re-arm accumulator every call

  __shared__ float sA[4][4], sB[4][4], sM[4][4];
  float hv[4];
#pragma unroll
  for (int r = 0; r < 4; ++r) {
    const int idx = (i0 + r) * DD + t;
    const float x = X[idx], h = H[idx], c = C[idx];
    const int m = M[idx];
    hv[r] = h;
    const float e = m ? (x - h + c) : 0.0f;
    float pm = e * e, ph = h, ph2 = h * h;
#pragma unroll
    for (int s = 1; s < 64; s <<= 1) {
      pm  += __shfl_xor(pm, s);
      ph  += __shfl_xor(ph, s);
      ph2 += __shfl_xor(ph2, s);
    }
    const ull bal = __ballot(m != 0);
    if (lane == 0) {
      sA[r][wid] = ph; sB[r][wid] = ph2; sM[r][wid] = pm;
      MB[(i0 + r) * 4 + wid] = bal;
    }
  }
  // transpose write: ht[d=t][i0..i0+3], 16B aligned, full sectors
  *(float4*)(ht + t * TT + i0) = make_float4(hv[0], hv[1], hv[2], hv[3]);
  __syncthreads();
  if (t < 4) {
    A[i0 + t] = sA[t][0] + sA[t][1] + sA[t][2] + sA[t][3];
    B[i0 + t] = sB[t][0] + sB[t][1] + sB[t][2] + sB[t][3];
  }
  if (t == 0) {
    float ms = 0.0f;
#pragma unroll
    for (int r = 0; r < 4; ++r)
#pragma unroll
      for (int wq = 0; wq < 4; ++wq) ms += sM[r][wq];
    MSEP4[b] = ms;
  }
}

// 256 blocks x 512 threads (8 waves). Block owns rows {2b, 2b+1}; thread t
// owns column j=t. i-operand from LDS (broadcast, latency-hideable);
// j-operand coalesced 4B/lane from transposed ht; 8-deep explicit load
// batches keep VMEM in flight (fixes the r6/r7 latency serialization).
__global__ __launch_bounds__(512, 2) void score_kernel(
    const float* __restrict__ H, const float* __restrict__ ht,
    const float* __restrict__ A, const float* __restrict__ B,
    const ull* __restrict__ MB, const float* __restrict__ MSEP4,
    float* __restrict__ out) {
  __shared__ float2 hi2[DD];      // 2 KB: both i-rows interleaved
  __shared__ float dl[2][TT];     // 4 KB scores
  __shared__ float nrm[2][TT];    // 4 KB norms
  __shared__ float s_rl[2];

  const int b = blockIdx.x;
  const int t = threadIdx.x;
  const int wv = t >> 6, lane = t & 63;
  const int i0 = 2 * b;

  // stage the 2 i-rows into LDS (coalesced global, 2-way LDS write ok)
  if (t < DD) {
    const float v0 = H[i0 * DD + t];
    const float v1 = H[(i0 + 1) * DD + t];
    hi2[t] = make_float2(v0, v1);
  }
  __syncthreads();

  // dot + on-the-fly a_j, b_j
  float acc0 = 0.f, acc1 = 0.f, aj = 0.f, bj = 0.f;
  {
    const float* __restrict__ hjp = ht + t;
    for (int d0 = 0; d0 < DD; d0 += 8) {
      float hjv[8];
#pragma unroll
      for (int k = 0; k < 8; ++k) hjv[k] = hjp[(d0 + k) * TT];  // coalesced
      float2 hiv[8];
#pragma unroll
      for (int k = 0; k < 8; ++k) hiv[k] = hi2[d0 + k];         // broadcast
#pragma unroll
      for (int k = 0; k < 8; ++k) {
        acc0 += hiv[k].x * hjv[k];
        acc1 += hiv[k].y * hjv[k];
        aj += hjv[k];
        bj += hjv[k] * hjv[k];
      }
    }
  }

  // scores + norms for (i0..i0+1, j=t)
  {
    const float ai0 = A[i0], ai1 = A[i0 + 1];
    const float bi0 = B[i0], bi1 = B[i0 + 1];
    const ull mj0 = MB[t * 4 + 0], mj1 = MB[t * 4 + 1],
              mj2 = MB[t * 4 + 2], mj3 = MB[t * 4 + 3];
    const ull n00 = MB[i0 * 4 + 0], n01 = MB[i0 * 4 + 1],
              n02 = MB[i0 * 4 + 2], n03 = MB[i0 * 4 + 3];
    const ull n10 = MB[(i0 + 1) * 4 + 0], n11 = MB[(i0 + 1) * 4 + 1],
              n12 = MB[(i0 + 1) * 4 + 2], n13 = MB[(i0 + 1) * 4 + 3];
    {
      const float s2 = bi0 + bj - 2.0f * acc0;
      const float s1 = ai0 - aj;
      const float var = (s2 - s1 * s1 * (1.0f / DD)) * (1.0f / (DD - 1));
      const bool diff = (mj0 != n00) | (mj1 != n01) | (mj2 != n02) | (mj3 != n03);
      const bool valid = diff && (t != i0);
      dl[0][t] = valid ? sqrtf(fmaxf(var, 0.0f)) : BIGF;
      nrm[0][t] = sqrtf(fmaxf(s2, 0.0f));
    }
    {
      const float s2 = bi1 + bj - 2.0f * acc1;
      const float s1 = ai1 - aj;
      const float var = (s2 - s1 * s1 * (1.0f / DD)) * (1.0f / (DD - 1));
      const bool diff = (mj0 != n10) | (mj1 != n11) | (mj2 != n12) | (mj3 != n13);
      const bool valid = diff && (t != i0 + 1);
      dl[1][t] = valid ? sqrtf(fmaxf(var, 0.0f)) : BIGF;
      nrm[1][t] = sqrtf(fmaxf(s2, 0.0f));
    }
  }
  __syncthreads();

  // waves 0-1: per-row iterative top-8 smallest (lowest-index tie-break)
  if (wv < 2) {
    const int w = wv;
    float cv[8];
#pragma unroll
    for (int c = 0; c < 8; ++c) cv[c] = dl[w][lane + 64 * c];

    float kv[KK];
    int ki[KK];
#pragma unroll
    for (int k = 0; k < KK; ++k) {
      float bv = cv[0];
      int bc = 0;
#pragma unroll
      for (int c = 1; c < 8; ++c) {
        if (cv[c] < bv) { bv = cv[c]; bc = c; }
      }
      int bidx = lane + 64 * bc;
#pragma unroll
      for (int s = 1; s < 64; s <<= 1) {
        const float ov = __shfl_xor(bv, s);
        const int oi = __shfl_xor(bidx, s);
        if (ov < bv || (ov == bv && oi < bidx)) { bv = ov; bidx = oi; }
      }
      kv[k] = bv;
      ki[k] = bidx;
      const int csel = bidx >> 6;
      const bool mine = (bidx & 63) == lane;
#pragma unroll
      for (int c = 0; c < 8; ++c) {
        if (mine && c == csel) cv[c] = BIGF;
      }
    }
    float wsum = 0.0f, rl = 0.0f;
#pragma unroll
    for (int k = 0; k < KK; ++k) {
      const float e = expf(kv[0] - kv[k]);  // kv[0] = min score
      wsum += e;
      rl += e * nrm[w][ki[k]];
    }
    if (lane == 0) s_rl[w] = rl / wsum;
  }
  __syncthreads();

  if (t == 0) {
    float part = s_rl[0] + s_rl[1];
    if ((b & 1) == 0) part += MSEP4[b >> 1];  // 4-row MSE group on even blocks
    atomicAdd(out, part);
  }
}

extern "C" void kernel_launch(void* const* d_in, const int* in_sizes, int n_in,
                              void* d_out, int out_size, void* d_ws, size_t ws_size,
                              hipStream_t stream) {
  const float* X = (const float*)d_in[0];
  const float* H = (const float*)d_in[1];
  const float* C = (const float*)d_in[2];
  const int* M = (const int*)d_in[3];
  float* out = (float*)d_out;

  char* ws = (char*)d_ws;
  float* ht = (float*)(ws + HT_OFF);
  float* A = (float*)(ws + A_OFF);
  float* B = (float*)(ws + B_OFF);
  ull* MB = (ull*)(ws + MB_OFF);
  float* MSEP4 = (float*)(ws + MSEP_OFF);

  prep_kernel<<<128, 256, 0, stream>>>(X, H, C, M, ht, A, B, MB, MSEP4, out);
  score_kernel<<<256, 512, 0, stream>>>(H, ht, A, B, MB, MSEP4, out);
}

// Round 10
// 38.482 us; speedup vs baseline: 5.9668x; 5.9668x over previous
//
#include <hip/hip_runtime.h>
#include <math.h>

#define TT 512
#define DD 256
#define BIGF 9999.0f
#define KK 8
#define NBLK 128   // 4 rows per block, both kernels

// ws layout (bytes)
#define HT_OFF    0          // float ht[DD][TT]   512 KB  transposed H
#define A_OFF     524288     // float a[TT]
#define B_OFF     526336     // float b[TT]
#define MB_OFF    528384     // ull   mb[TT][4]
#define MSEP_OFF  544768     // float msep4[NBLK]  per-4-row-group masked MSE

typedef unsigned long long ull;

__global__ __launch_bounds__(256) void prep_kernel(
    const float* __restrict__ X, const float* __restrict__ H,
    const float* __restrict__ C, const int* __restrict__ M,
    float* __restrict__ ht, float* __restrict__ A, float* __restrict__ B,
    ull* __restrict__ MB, float* __restrict__ MSEP4, float* __restrict__ out) {
  const int b = blockIdx.x;
  const int t = threadIdx.x;
  const int wid = t >> 6, lane = t & 63;
  const int i0 = 4 * b;
  if (b == 0 && t == 0) out[0] = 0.0f;  // re-arm accumulator every call

  __shared__ float sA[4][4], sB[4][4], sM[4][4];
  float hv[4];
#pragma unroll
  for (int r = 0; r < 4; ++r) {
    const int idx = (i0 + r) * DD + t;
    const float x = X[idx], h = H[idx], c = C[idx];
    const int m = M[idx];
    hv[r] = h;
    const float e = m ? (x - h + c) : 0.0f;
    float pm = e * e, ph = h, ph2 = h * h;
#pragma unroll
    for (int s = 1; s < 64; s <<= 1) {
      pm  += __shfl_xor(pm, s);
      ph  += __shfl_xor(ph, s);
      ph2 += __shfl_xor(ph2, s);
    }
    const ull bal = __ballot(m != 0);
    if (lane == 0) {
      sA[r][wid] = ph; sB[r][wid] = ph2; sM[r][wid] = pm;
      MB[(i0 + r) * 4 + wid] = bal;
    }
  }
  // transpose write: ht[d=t][i0..i0+3], 16B aligned, full sectors
  *(float4*)(ht + t * TT + i0) = make_float4(hv[0], hv[1], hv[2], hv[3]);
  __syncthreads();
  if (t < 4) {
    A[i0 + t] = sA[t][0] + sA[t][1] + sA[t][2] + sA[t][3];
    B[i0 + t] = sB[t][0] + sB[t][1] + sB[t][2] + sB[t][3];
  }
  if (t == 0) {
    float ms = 0.0f;
#pragma unroll
    for (int r = 0; r < 4; ++r)
#pragma unroll
      for (int wq = 0; wq < 4; ++wq) ms += sM[r][wq];
    MSEP4[b] = ms;
  }
}

// 128 blocks x 256 threads (r6-proven shape). Block owns rows i0..i0+3;
// thread t owns j={2t,2t+1}. i-operand via LDS broadcast (no SMEM chain);
// d split into 4 INDEPENDENT chains (d, d+64, d+128, d+192) so >=4 j-loads
// are always in flight -> breaks the 256-step serial latency chain.
__global__ __launch_bounds__(256) void score_kernel(
    const float* __restrict__ H, const float* __restrict__ ht,
    const float* __restrict__ A, const float* __restrict__ B,
    const ull* __restrict__ MB, const float* __restrict__ MSEP4,
    float* __restrict__ out) {
  __shared__ float4 his[DD];      // 4 KB: rows i0..i0+3 at each d
  __shared__ float dl[4][TT];     // 8 KB scores
  __shared__ float nrm[4][TT];    // 8 KB norms
  __shared__ float s_rl[4];

  const int b = blockIdx.x;
  const int t = threadIdx.x;
  const int wid = t >> 6, lane = t & 63;
  const int i0 = 4 * b;

  // stage the 4 i-rows into LDS (4 coalesced 1KB loads)
  {
    const float v0 = H[(i0 + 0) * DD + t];
    const float v1 = H[(i0 + 1) * DD + t];
    const float v2 = H[(i0 + 2) * DD + t];
    const float v3 = H[(i0 + 3) * DD + t];
    his[t] = make_float4(v0, v1, v2, v3);
  }
  __syncthreads();

  // dot phase: 4 independent d-chains, 8 acc each
  float acc[4][4][2];
#pragma unroll
  for (int c = 0; c < 4; ++c)
#pragma unroll
    for (int r = 0; r < 4; ++r) {
      acc[c][r][0] = 0.f;
      acc[c][r][1] = 0.f;
    }
  {
    const float* __restrict__ pj = ht + 2 * t;
#pragma unroll 4
    for (int d0 = 0; d0 < 64; ++d0) {
      float2 hj[4];
      float4 hi[4];
#pragma unroll
      for (int c = 0; c < 4; ++c) {
        const int d = d0 + 64 * c;
        hj[c] = *(const float2*)(pj + d * TT);  // coalesced 512B/wave
        hi[c] = his[d];                          // LDS broadcast b128
      }
#pragma unroll
      for (int c = 0; c < 4; ++c) {
        acc[c][0][0] += hi[c].x * hj[c].x; acc[c][0][1] += hi[c].x * hj[c].y;
        acc[c][1][0] += hi[c].y * hj[c].x; acc[c][1][1] += hi[c].y * hj[c].y;
        acc[c][2][0] += hi[c].z * hj[c].x; acc[c][2][1] += hi[c].z * hj[c].y;
        acc[c][3][0] += hi[c].w * hj[c].x; acc[c][3][1] += hi[c].w * hj[c].y;
      }
    }
  }
  // merge the 4 chains
  float accm[4][2];
#pragma unroll
  for (int r = 0; r < 4; ++r)
#pragma unroll
    for (int jj = 0; jj < 2; ++jj)
      accm[r][jj] = (acc[0][r][jj] + acc[1][r][jj]) +
                    (acc[2][r][jj] + acc[3][r][jj]);

  float ai[4], bi[4];
  ull mi[4][4];
#pragma unroll
  for (int r = 0; r < 4; ++r) {
    ai[r] = A[i0 + r];
    bi[r] = B[i0 + r];
#pragma unroll
    for (int c = 0; c < 4; ++c) mi[r][c] = MB[(i0 + r) * 4 + c];
  }

#pragma unroll
  for (int jj = 0; jj < 2; ++jj) {
    const int j = 2 * t + jj;
    const float aj = A[j], bj = B[j];
    const ull m0 = MB[j * 4 + 0], m1 = MB[j * 4 + 1],
              m2 = MB[j * 4 + 2], m3 = MB[j * 4 + 3];
#pragma unroll
    for (int r = 0; r < 4; ++r) {
      const float dot = accm[r][jj];
      const float s2 = bi[r] + bj - 2.0f * dot;
      const float s1 = ai[r] - aj;
      const float var = (s2 - s1 * s1 * (1.0f / DD)) * (1.0f / (DD - 1));
      const bool diff = (m0 != mi[r][0]) | (m1 != mi[r][1]) |
                        (m2 != mi[r][2]) | (m3 != mi[r][3]);
      const bool valid = diff && (j != i0 + r);
      dl[r][j] = valid ? sqrtf(fmaxf(var, 0.0f)) : BIGF;
      nrm[r][j] = sqrtf(fmaxf(s2, 0.0f));
    }
  }
  __syncthreads();

  // wave w -> row i0+w: iterative top-8 smallest, lowest-index tie-break
  {
    const int w = wid;
    float cv[8];
#pragma unroll
    for (int c = 0; c < 8; ++c) cv[c] = dl[w][lane + 64 * c];

    float kv[KK];
    int ki[KK];
#pragma unroll
    for (int k = 0; k < KK; ++k) {
      float bv = cv[0];
      int bc = 0;
#pragma unroll
      for (int c = 1; c < 8; ++c) {
        if (cv[c] < bv) { bv = cv[c]; bc = c; }
      }
      int bidx = lane + 64 * bc;
#pragma unroll
      for (int s = 1; s < 64; s <<= 1) {
        const float ov = __shfl_xor(bv, s);
        const int oi = __shfl_xor(bidx, s);
        if (ov < bv || (ov == bv && oi < bidx)) { bv = ov; bidx = oi; }
      }
      kv[k] = bv;
      ki[k] = bidx;
      const int csel = bidx >> 6;
      const bool mine = (bidx & 63) == lane;
#pragma unroll
      for (int c = 0; c < 8; ++c) {
        if (mine && c == csel) cv[c] = BIGF;
      }
    }
    float wsum = 0.0f, rl = 0.0f;
#pragma unroll
    for (int k = 0; k < KK; ++k) {
      const float e = expf(kv[0] - kv[k]);  // kv[0] = min score
      wsum += e;
      rl += e * nrm[w][ki[k]];
    }
    if (lane == 0) s_rl[w] = rl / wsum;
  }
  __syncthreads();

  if (t == 0)
    atomicAdd(out, s_rl[0] + s_rl[1] + s_rl[2] + s_rl[3] + MSEP4[b]);
}

extern "C" void kernel_launch(void* const* d_in, const int* in_sizes, int n_in,
                              void* d_out, int out_size, void* d_ws, size_t ws_size,
                              hipStream_t stream) {
  const float* X = (const float*)d_in[0];
  const float* H = (const float*)d_in[1];
  const float* C = (const float*)d_in[2];
  const int* M = (const int*)d_in[3];
  float* out = (float*)d_out;

  char* ws = (char*)d_ws;
  float* ht = (float*)(ws + HT_OFF);
  float* A = (float*)(ws + A_OFF);
  float* B = (float*)(ws + B_OFF);
  ull* MB = (ull*)(ws + MB_OFF);
  float* MSEP4 = (float*)(ws + MSEP_OFF);

  prep_kernel<<<NBLK, 256, 0, stream>>>(X, H, C, M, ht, A, B, MB, MSEP4, out);
  score_kernel<<<NBLK, 256, 0, stream>>>(H, ht, A, B, MB, MSEP4, out);
}